// Round 7
// baseline (132.968 us; speedup 1.0000x reference)
//
#include <hip/hip_runtime.h>

// MPS classifier: logits[b,o] = (v/||v||)·cls[o] + log||v||,
//   v = head0(b) · M_1(b) · ... · M_783(b),  M_n = A_n + x[b,n]*(B_n - A_n).
// Chain associative; normalizations telescope.
//   K0: repack cores -> per-site float4 (A_2q, A_2q+1, D_2q, D_2q+1)
//   K1: ONE sample per lane, full 10x10 running product in registers,
//       IN-PLACE row update (p[r] = p[r]·M) with the whole blended M
//       register-resident -> no ping-pong, live set ~215 VGPR, no spill.
//       Each wave-level broadcast ds_read_b128 now feeds a full 1000-FMA
//       site (halves total LDS-pipe instructions vs the 2-lane split).
//   K2: pbuf [chunk][sample][100] contiguous; depth-8 prefetch ring;
//       renorm deferred to every 8th chunk.

typedef float f32x2 __attribute__((ext_vector_type(2)));

constexpr int Bsz  = 2048;
constexpr int Nn   = 784;
constexpr int NS   = 783;
constexpr int MAXL = 16;

// packed fp32 helpers (VOP3P). D = S0*S1 + S2.
#define PK_FMA(d, a, b, c) \
  asm("v_pk_fma_f32 %0, %1, %2, %3" : "=v"(d) : "v"(a), "v"(b), "v"(c))
#define PK_FMA_ACC_LO(d, m, s) \
  asm("v_pk_fma_f32 %0, %1, %2, %0 op_sel:[0,0,0] op_sel_hi:[1,0,1]" \
      : "+v"(d) : "v"(m), "v"(s))
#define PK_FMA_ACC_HI(d, m, s) \
  asm("v_pk_fma_f32 %0, %1, %2, %0 op_sel:[0,1,0] op_sel_hi:[1,1,1]" \
      : "+v"(d) : "v"(m), "v"(s))
#define PK_MUL_LO(d, m, s) \
  asm("v_pk_mul_f32 %0, %1, %2 op_sel:[0,0] op_sel_hi:[1,0]" \
      : "=v"(d) : "v"(m), "v"(s))

// ---------------- K0: repack weights ----------------
__global__ void repack_kernel(const float* __restrict__ cores,
                              float4* __restrict__ rw4) {
    int tid = blockIdx.x * blockDim.x + threadIdx.x;
    if (tid >= NS * 50) return;
    int k = tid / 50;
    int e = tid - k * 50;
    int i = e / 5, q = e - i * 5;
    const float a0 = cores[k * 200 + i * 20 + 2 * q];
    const float a1 = cores[k * 200 + i * 20 + 2 * q + 1];
    const float b0 = cores[k * 200 + i * 20 + 10 + 2 * q];
    const float b1 = cores[k * 200 + i * 20 + 10 + 2 * q + 1];
    float4 w;
    w.x = a0; w.y = a1; w.z = b0 - a0; w.w = b1 - a1;
    rw4[k * 50 + i * 5 + q] = w;
}

// ---------------- K1: one sample per lane, in-place row update ------------
__global__ __launch_bounds__(256, 1) void chunk_kernel(
    const float* __restrict__ x, const float4* __restrict__ rw4,
    float* __restrict__ pbuf, float* __restrict__ lbuf, int L) {
    __shared__ float4 s_w[MAXL * 50];   // chunk weights, paired layout
    __shared__ float  s_x[256 * 17];    // per-sample x slice, stride 17

    const int c   = blockIdx.y;
    const int n0  = 1 + c * L;
    const int n1  = min(n0 + L, Nn);
    const int ns  = n1 - n0;
    const int tid = (int)threadIdx.x;
    const int b0  = (int)blockIdx.x * 256;
    const int b   = b0 + tid;

    const float4* gw = rw4 + (size_t)(n0 - 1) * 50;
    for (int idx = tid; idx < ns * 50; idx += 256) s_w[idx] = gw[idx];
    for (int e = tid; e < 256 * 16; e += 256) {
        int bl = e >> 4, k = e & 15;
        if (k < ns) s_x[bl * 17 + k] = x[(size_t)(b0 + bl) * Nn + n0 + k];
    }
    __syncthreads();

    const float* __restrict__ xs = s_x + tid * 17;

    f32x2 p[10][5];                     // full 10x10 running product
    {   // first site: P = M
        const float xv = xs[0];
        const f32x2 x2 = {xv, xv};
#pragma unroll
        for (int i = 0; i < 10; ++i)
#pragma unroll
            for (int q = 0; q < 5; ++q) {
                const float4 w = s_w[i * 5 + q];
                const f32x2 a = {w.x, w.y}, dd = {w.z, w.w};
                PK_FMA(p[i][q], dd, x2, a);
            }
    }

    for (int k = 1; k < ns; ++k) {
        const float xv = xs[k];
        const f32x2 x2 = {xv, xv};
        const float4* wp = s_w + k * 50;

        // blend full M into registers (50 f32x2)
        f32x2 M[10][5];
#pragma unroll
        for (int i = 0; i < 10; ++i)
#pragma unroll
            for (int q = 0; q < 5; ++q) {
                const float4 w = wp[i * 5 + q];
                const f32x2 a = {w.x, w.y}, dd = {w.z, w.w};
                PK_FMA(M[i][q], dd, x2, a);
            }

        // in-place: p[r] = p[r] · M   (row r fully read before overwrite)
#pragma unroll
        for (int r = 0; r < 10; ++r) {
            f32x2 acc[5];
#pragma unroll
            for (int q = 0; q < 5; ++q) PK_MUL_LO(acc[q], M[0][q], p[r][0]);
#pragma unroll
            for (int q = 0; q < 5; ++q) PK_FMA_ACC_HI(acc[q], M[1][q], p[r][0]);
#pragma unroll
            for (int ip = 1; ip < 5; ++ip) {
#pragma unroll
                for (int q = 0; q < 5; ++q)
                    PK_FMA_ACC_LO(acc[q], M[2 * ip][q], p[r][ip]);
#pragma unroll
                for (int q = 0; q < 5; ++q)
                    PK_FMA_ACC_HI(acc[q], M[2 * ip + 1][q], p[r][ip]);
            }
#pragma unroll
            for (int q = 0; q < 5; ++q) p[r][q] = acc[q];
        }
    }

    // Frobenius renorm once per chunk (all within lane)
    f32x2 ss = {0.f, 0.f};
#pragma unroll
    for (int r = 0; r < 10; ++r)
#pragma unroll
        for (int q = 0; q < 5; ++q) PK_FMA(ss, p[r][q], p[r][q], ss);
    float s = ss.x + ss.y;
    s = fmaxf(s, 1e-30f);
    const float rin = rsqrtf(s);
    lbuf[(size_t)c * Bsz + b] = 0.5f * __logf(s);

    // store this sample's 100 floats contiguously: pbuf[(c*Bsz + b)*100 + e]
    float2* dst = (float2*)(pbuf + ((size_t)c * Bsz + b) * 100);
#pragma unroll
    for (int r = 0; r < 10; ++r)
#pragma unroll
        for (int q = 0; q < 5; ++q) {
            float2 v;
            v.x = p[r][q].x * rin;
            v.y = p[r][q].y * rin;
            dst[r * 5 + q] = v;
        }
}

// ---------------- K2: combine chunks + logits (16 lanes per sample) --------
__global__ __launch_bounds__(256, 2) void combine_kernel(
    const float* __restrict__ x, const float* __restrict__ core0,
    const float* __restrict__ cls, const float* __restrict__ pbuf,
    const float* __restrict__ lbuf, float* __restrict__ out, int C) {
    const int tid   = (int)threadIdx.x;
    const int j     = tid & 15;
    const int jj    = (j < 10) ? j : 9;
    const int gbase = tid & 48;
    const int b     = blockIdx.x * 16 + (tid >> 4);

    float v[10];
    const float x0 = x[(size_t)b * Nn];
#pragma unroll
    for (int i = 0; i < 10; ++i) {
        const float c0 = core0[i], c1 = core0[10 + i];
        v[i] = fmaf(x0, c1 - c0, c0);
    }

    // depth-8 prefetch ring, statically indexed; per-chunk data contiguous
    float w[8][10];
#pragma unroll
    for (int k8 = 0; k8 < 8; ++k8) {
        if (k8 < C) {
            const float* pn = pbuf + ((size_t)k8 * Bsz + b) * 100 + jj;
#pragma unroll
            for (int i = 0; i < 10; ++i) w[k8][i] = pn[i * 10];
        }
    }

    float llog = 0.f;
    for (int cg = 0; cg < C; cg += 8) {
#pragma unroll
        for (int k8 = 0; k8 < 8; ++k8) {
            const int c = cg + k8;
            if (c >= C) break;
            float acc = 0.f;
#pragma unroll
            for (int i = 0; i < 10; ++i) acc = fmaf(v[i], w[k8][i], acc);
            if (j >= 10) acc = 0.f;
            llog += lbuf[(size_t)c * Bsz + b];
            if (k8 == 7 || c == C - 1) {   // deferred renorm
                float s = acc * acc;
                s += __shfl_xor(s, 1);
                s += __shfl_xor(s, 2);
                s += __shfl_xor(s, 4);
                s += __shfl_xor(s, 8);
                s = fmaxf(s, 1e-30f);
                llog += 0.5f * __logf(s);
                acc *= rsqrtf(s);
            }
#pragma unroll
            for (int i = 0; i < 10; ++i) v[i] = __shfl(acc, gbase + i);
            if (c + 8 < C) {               // refill the slot just consumed
                const float* pn = pbuf + ((size_t)(c + 8) * Bsz + b) * 100 + jj;
#pragma unroll
                for (int i = 0; i < 10; ++i) w[k8][i] = pn[i * 10];
            }
        }
    }

    if (j < 10) {
        float acc = llog;
#pragma unroll
        for (int i = 0; i < 10; ++i) acc = fmaf(v[i], cls[j * 10 + i], acc);
        out[(size_t)b * 10 + j] = acc;
    }
}

// ---------------- launch ----------------
extern "C" void kernel_launch(void* const* d_in, const int* in_sizes, int n_in,
                              void* d_out, int out_size, void* d_ws, size_t ws_size,
                              hipStream_t stream) {
    const float* x     = (const float*)d_in[0];
    const float* core0 = (const float*)d_in[1];
    const float* cores = (const float*)d_in[2];
    const float* cls   = (const float*)d_in[3];
    float* out = (float*)d_out;

    float4* rw4 = (float4*)d_ws;                    // NS*50 float4
    size_t off = ((size_t)NS * 200 * 4 + 255) & ~(size_t)255;
    size_t per_chunk = (size_t)100 * Bsz * 4 + (size_t)Bsz * 4;  // P + log
    size_t avail = ws_size > off ? ws_size - off : 0;
    int C = (int)(avail / per_chunk);
    if (C > 61) C = 61;
    if (C < 1)  C = 1;
    int L = (NS + C - 1) / C;
    if (L > MAXL) L = MAXL;                         // LDS capacity guard
    C = (NS + L - 1) / L;                           // tighten
    float* pbuf = (float*)((char*)d_ws + off);
    float* lbuf = pbuf + (size_t)C * 100 * Bsz;

    hipLaunchKernelGGL(repack_kernel, dim3((NS * 50 + 255) / 256), dim3(256),
                       0, stream, cores, rw4);
    hipLaunchKernelGGL(chunk_kernel, dim3(Bsz / 256, C), dim3(256),
                       0, stream, x, rw4, pbuf, lbuf, L);
    hipLaunchKernelGGL(combine_kernel, dim3(Bsz / 16), dim3(256),
                       0, stream, x, core0, cls, pbuf, lbuf, out, C);
}

// Round 8
// 128.678 us; speedup vs baseline: 1.0333x; 1.0333x over previous
//
#include <hip/hip_runtime.h>

// MPS classifier: logits[b,o] = (v/||v||)·cls[o] + log||v||,
//   v = head0(b) · M_1(b) · ... · M_783(b),  M_n = A_n + x[b,n]*(B_n - A_n).
// Chain associative; normalizations telescope.
//   K0: repack cores -> per-site float4 (A_2q, A_2q+1, D_2q, D_2q+1)
//   K1: 2 lanes per sample own 5 rows each of the running 10x10 product
//       (f32x2 pairs, v_pk_fma) -- the proven no-spill shape (VGPR 84-108).
//       WEIGHTS now read via wave-uniform global loads -> s_load (SMEM/K$
//       pipe), NOT LDS: round-5 was LDS-pipe-bound (50 b128/site/wave x 12cy
//       = 49us measured == model). Blend uses the 1-SGPR-operand slot:
//       t = pk_mul(s_dd, x2); m = pk_add(s_a, t). LDS holds only x.
//   K2: pbuf [chunk][sample][100] contiguous; depth-8 prefetch ring;
//       renorm deferred to every 8th chunk.

typedef float f32x2 __attribute__((ext_vector_type(2)));

constexpr int Bsz  = 2048;
constexpr int Nn   = 784;
constexpr int NS   = 783;
constexpr int MAXL = 16;

// VOP3P helpers (plain syntax = standard packed semantics).
#define PK_FMA(d, a, b, c) \
  asm("v_pk_fma_f32 %0, %1, %2, %3" : "=v"(d) : "v"(a), "v"(b), "v"(c))
#define PK_FMA_ACC_LO(d, m, s) \
  asm("v_pk_fma_f32 %0, %1, %2, %0 op_sel:[0,0,0] op_sel_hi:[1,0,1]" \
      : "+v"(d) : "v"(m), "v"(s))
#define PK_FMA_ACC_HI(d, m, s) \
  asm("v_pk_fma_f32 %0, %1, %2, %0 op_sel:[0,1,0] op_sel_hi:[1,1,1]" \
      : "+v"(d) : "v"(m), "v"(s))
#define PK_MUL_LO(d, m, s) \
  asm("v_pk_mul_f32 %0, %1, %2 op_sel:[0,0] op_sel_hi:[1,0]" \
      : "=v"(d) : "v"(m), "v"(s))
// blend with scalar-register weights (1 SGPR operand per instr, legal):
#define PK_MUL_S(t, ds_, x2_) \
  asm("v_pk_mul_f32 %0, %1, %2" : "=v"(t) : "s"(ds_), "v"(x2_))
#define PK_ADD_S(m, as_, t_) \
  asm("v_pk_add_f32 %0, %1, %2" : "=v"(m) : "s"(as_), "v"(t_))

// ---------------- K0: repack weights ----------------
__global__ void repack_kernel(const float* __restrict__ cores,
                              float4* __restrict__ rw4) {
    int tid = blockIdx.x * blockDim.x + threadIdx.x;
    if (tid >= NS * 50) return;
    int k = tid / 50;
    int e = tid - k * 50;
    int i = e / 5, q = e - i * 5;
    const float a0 = cores[k * 200 + i * 20 + 2 * q];
    const float a1 = cores[k * 200 + i * 20 + 2 * q + 1];
    const float b0 = cores[k * 200 + i * 20 + 10 + 2 * q];
    const float b1 = cores[k * 200 + i * 20 + 10 + 2 * q + 1];
    float4 w;
    w.x = a0; w.y = a1; w.z = b0 - a0; w.w = b1 - a1;
    rw4[k * 50 + i * 5 + q] = w;
}

// ---------------- K1: dst(5x10) = src(5x10) * M(site), SMEM weights -------
__device__ __forceinline__ void site_step(const float4* __restrict__ wp,
                                          const f32x2 x2,
                                          const f32x2 (&src)[5][5],
                                          f32x2 (&dst)[5][5]) {
#pragma unroll
    for (int ip = 0; ip < 5; ++ip) {
        f32x2 m0[5], m1[5];           // M rows 2*ip and 2*ip+1 (blended)
#pragma unroll
        for (int qq = 0; qq < 5; ++qq) {
            const float4 w0 = wp[(2 * ip) * 5 + qq];       // uniform -> s_load
            const float4 w1 = wp[(2 * ip + 1) * 5 + qq];
            const f32x2 a0 = {w0.x, w0.y}, d0 = {w0.z, w0.w};
            const f32x2 a1 = {w1.x, w1.y}, d1 = {w1.z, w1.w};
            f32x2 t0, t1;
            PK_MUL_S(t0, d0, x2);
            PK_ADD_S(m0[qq], a0, t0);
            PK_MUL_S(t1, d1, x2);
            PK_ADD_S(m1[qq], a1, t1);
        }
        if (ip == 0) {
#pragma unroll
            for (int r = 0; r < 5; ++r) {
                const f32x2 s2 = src[r][0];
#pragma unroll
                for (int qq = 0; qq < 5; ++qq) {
                    PK_MUL_LO(dst[r][qq], m0[qq], s2);
                    PK_FMA_ACC_HI(dst[r][qq], m1[qq], s2);
                }
            }
        } else {
#pragma unroll
            for (int r = 0; r < 5; ++r) {
                const f32x2 s2 = src[r][ip];
#pragma unroll
                for (int qq = 0; qq < 5; ++qq) {
                    PK_FMA_ACC_LO(dst[r][qq], m0[qq], s2);
                    PK_FMA_ACC_HI(dst[r][qq], m1[qq], s2);
                }
            }
        }
    }
}

__global__ __launch_bounds__(256, 3) void chunk_kernel(
    const float* __restrict__ x, const float4* __restrict__ rw4,
    float* __restrict__ pbuf, float* __restrict__ lbuf, int L) {
    __shared__ float s_x[128 * 17];     // x slice only (weights go via SMEM)

    const int c   = blockIdx.y;
    const int n0  = 1 + c * L;
    const int n1  = min(n0 + L, Nn);
    const int ns  = n1 - n0;
    const int tid = (int)threadIdx.x;
    const int b0  = (int)blockIdx.x * 128;

    for (int e = tid; e < 128 * 16; e += 256) {
        int bl = e >> 4, k = e & 15;
        if (k < ns) s_x[bl * 17 + k] = x[(size_t)(b0 + bl) * Nn + n0 + k];
    }
    __syncthreads();

    const int h = tid & 1;              // row-half owner
    const int u = tid >> 1;             // sample slot 0..127
    const int b = b0 + u;
    const float* __restrict__ xs = s_x + u * 17;

    const float4* wp = rw4 + (size_t)(n0 - 1) * 50;   // uniform pointer

    f32x2 p[5][5], q2[5][5];
    {   // first site: P = M (rows 5h..5h+4), blended from SGPR weights
        const float xv = xs[0];
        const f32x2 x2 = {xv, xv};
#pragma unroll
        for (int r = 0; r < 5; ++r) {
#pragma unroll
            for (int qq = 0; qq < 5; ++qq) {
                const float4 w = wp[(5 * h + r) * 5 + qq];
                const f32x2 a = {w.x, w.y}, dd = {w.z, w.w};
                f32x2 t;
                PK_MUL_S(t, dd, x2);
                PK_ADD_S(p[r][qq], a, t);
            }
        }
    }
    int k = 1;
    wp += 50;
    while (k + 1 < ns) {
        const f32x2 xa = {xs[k], xs[k]};
        const f32x2 xc = {xs[k + 1], xs[k + 1]};
        site_step(wp,      xa, p, q2);
        site_step(wp + 50, xc, q2, p);
        wp += 100;
        k  += 2;
    }
    if (k < ns) {   // even-ns tail
        const f32x2 xa = {xs[k], xs[k]};
        site_step(wp, xa, p, q2);
#pragma unroll
        for (int r = 0; r < 5; ++r)
#pragma unroll
            for (int qq = 0; qq < 5; ++qq) p[r][qq] = q2[r][qq];
    }

    // Frobenius renorm once per chunk (pair-reduce via shfl_xor lane-pair)
    f32x2 ss = {0.f, 0.f};
#pragma unroll
    for (int r = 0; r < 5; ++r)
#pragma unroll
        for (int qq = 0; qq < 5; ++qq) PK_FMA(ss, p[r][qq], p[r][qq], ss);
    float s = ss.x + ss.y;
    s += __shfl_xor(s, 1);
    s = fmaxf(s, 1e-30f);
    const float rin = rsqrtf(s);
    if (h == 0) lbuf[(size_t)c * Bsz + b] = 0.5f * __logf(s);

    // store per-sample CONTIGUOUS 100-float block: pbuf[(c*Bsz + b)*100 + e]
    float2* dst = (float2*)(pbuf + ((size_t)c * Bsz + b) * 100);
#pragma unroll
    for (int r = 0; r < 5; ++r)
#pragma unroll
        for (int qq = 0; qq < 5; ++qq) {
            float2 v;
            v.x = p[r][qq].x * rin;
            v.y = p[r][qq].y * rin;
            dst[(5 * h + r) * 5 + qq] = v;
        }
}

// ---------------- K2: combine chunks + logits (16 lanes per sample) --------
__global__ __launch_bounds__(256, 2) void combine_kernel(
    const float* __restrict__ x, const float* __restrict__ core0,
    const float* __restrict__ cls, const float* __restrict__ pbuf,
    const float* __restrict__ lbuf, float* __restrict__ out, int C) {
    const int tid   = (int)threadIdx.x;
    const int j     = tid & 15;
    const int jj    = (j < 10) ? j : 9;
    const int gbase = tid & 48;
    const int b     = blockIdx.x * 16 + (tid >> 4);

    float v[10];
    const float x0 = x[(size_t)b * Nn];
#pragma unroll
    for (int i = 0; i < 10; ++i) {
        const float c0 = core0[i], c1 = core0[10 + i];
        v[i] = fmaf(x0, c1 - c0, c0);
    }

    // depth-8 prefetch ring, statically indexed; per-chunk data contiguous
    float w[8][10];
#pragma unroll
    for (int k8 = 0; k8 < 8; ++k8) {
        if (k8 < C) {
            const float* pn = pbuf + ((size_t)k8 * Bsz + b) * 100 + jj;
#pragma unroll
            for (int i = 0; i < 10; ++i) w[k8][i] = pn[i * 10];
        }
    }

    float llog = 0.f;
    for (int cg = 0; cg < C; cg += 8) {
#pragma unroll
        for (int k8 = 0; k8 < 8; ++k8) {
            const int c = cg + k8;
            if (c >= C) break;
            float acc = 0.f;
#pragma unroll
            for (int i = 0; i < 10; ++i) acc = fmaf(v[i], w[k8][i], acc);
            if (j >= 10) acc = 0.f;
            llog += lbuf[(size_t)c * Bsz + b];
            if (k8 == 7 || c == C - 1) {   // deferred renorm
                float s = acc * acc;
                s += __shfl_xor(s, 1);
                s += __shfl_xor(s, 2);
                s += __shfl_xor(s, 4);
                s += __shfl_xor(s, 8);
                s = fmaxf(s, 1e-30f);
                llog += 0.5f * __logf(s);
                acc *= rsqrtf(s);
            }
#pragma unroll
            for (int i = 0; i < 10; ++i) v[i] = __shfl(acc, gbase + i);
            if (c + 8 < C) {               // refill the slot just consumed
                const float* pn = pbuf + ((size_t)(c + 8) * Bsz + b) * 100 + jj;
#pragma unroll
                for (int i = 0; i < 10; ++i) w[k8][i] = pn[i * 10];
            }
        }
    }

    if (j < 10) {
        float acc = llog;
#pragma unroll
        for (int i = 0; i < 10; ++i) acc = fmaf(v[i], cls[j * 10 + i], acc);
        out[(size_t)b * 10 + j] = acc;
    }
}

// ---------------- launch ----------------
extern "C" void kernel_launch(void* const* d_in, const int* in_sizes, int n_in,
                              void* d_out, int out_size, void* d_ws, size_t ws_size,
                              hipStream_t stream) {
    const float* x     = (const float*)d_in[0];
    const float* core0 = (const float*)d_in[1];
    const float* cores = (const float*)d_in[2];
    const float* cls   = (const float*)d_in[3];
    float* out = (float*)d_out;

    float4* rw4 = (float4*)d_ws;                    // NS*50 float4
    size_t off = ((size_t)NS * 200 * 4 + 255) & ~(size_t)255;
    size_t per_chunk = (size_t)100 * Bsz * 4 + (size_t)Bsz * 4;  // P + log
    size_t avail = ws_size > off ? ws_size - off : 0;
    int C = (int)(avail / per_chunk);
    if (C > 61) C = 61;
    if (C < 1)  C = 1;
    int L = (NS + C - 1) / C;
    if (L > MAXL) L = MAXL;                         // s_x capacity guard
    C = (NS + L - 1) / L;                           // tighten
    float* pbuf = (float*)((char*)d_ws + off);
    float* lbuf = pbuf + (size_t)C * 100 * Bsz;

    hipLaunchKernelGGL(repack_kernel, dim3((NS * 50 + 255) / 256), dim3(256),
                       0, stream, cores, rw4);
    hipLaunchKernelGGL(chunk_kernel, dim3(Bsz / 128, C), dim3(256),
                       0, stream, x, rw4, pbuf, lbuf, L);
    hipLaunchKernelGGL(combine_kernel, dim3(Bsz / 16), dim3(256),
                       0, stream, x, core0, cls, pbuf, lbuf, out, C);
}

// Round 9
// 103.920 us; speedup vs baseline: 1.2795x; 1.2382x over previous
//
#include <hip/hip_runtime.h>

// MPS classifier: logits[b,o] = (v/||v||)·cls[o] + log||v||,
//   v = head0(b) · M_1(b) · ... · M_783(b),  M_n = A_n + x[b,n]*(B_n - A_n).
// Chain associative; normalizations telescope.
//
// K1 (chunk_kernel): per chunk of L=12 sites, ONE sample per lane keeps the
//   full 10x10 running product in f16 (h2 pairs, v_pk_fma_f16). Weights are
//   staged (fused-converted from `cores`) into LDS as f16 {2A, 2(B-A)} pairs:
//   25 ds_read_b128/site/wave (vs 50 f32) and 64 samples/wave (vs 32)
//   -> 4x less LDS-pipe work than the round-5 LDS-bound 49us kernel.
//   The x2.0 pre-scale (exact, exponent-only) keeps ||P|| ~ e^{+-1} inside a
//   chunk (raw decay ~0.5/site would underflow f16); corrected by
//   lbuf -= ns*ln2. M streamed per row-pair (10 regs) + P/Q ping-pong.
// K2 (combine_kernel): pbuf f16 [c][b][13 uint4]; depth-8 prefetch ring;
//   renorm deferred to every 8th chunk.

typedef _Float16 h2 __attribute__((ext_vector_type(2)));

constexpr int Bsz  = 2048;
constexpr int Nn   = 784;
constexpr int NS   = 783;
constexpr int MAXL = 16;     // LDS capacity bound (s_w / s_x stride 17)

// f16 VOP3P helpers. D = S0*S1 + S2 per half.
#define PKH_FMA(d, a, b, c) \
  asm("v_pk_fma_f16 %0, %1, %2, %3" : "=v"(d) : "v"(a), "v"(b), "v"(c))
// dst += m * s.lo (both halves use s's LOW half)
#define PKH_ACC_LO(d, m, s) \
  asm("v_pk_fma_f16 %0, %1, %2, %0 op_sel:[0,0,0] op_sel_hi:[1,0,1]" \
      : "+v"(d) : "v"(m), "v"(s))
// dst += m * s.hi
#define PKH_ACC_HI(d, m, s) \
  asm("v_pk_fma_f16 %0, %1, %2, %0 op_sel:[0,1,0] op_sel_hi:[1,1,1]" \
      : "+v"(d) : "v"(m), "v"(s))
// dst = m * s.lo
#define PKH_MUL_LO(d, m, s) \
  asm("v_pk_mul_f16 %0, %1, %2 op_sel:[0,0] op_sel_hi:[1,0]" \
      : "=v"(d) : "v"(m), "v"(s))

__device__ __forceinline__ h2 u2h(unsigned u) {
    union { unsigned u; h2 h; } c; c.u = u; return c.h;
}
__device__ __forceinline__ unsigned h2u(h2 h) {
    union { unsigned u; h2 h; } c; c.h = h; return c.u;
}

// dst(10x10) = src(10x10) * M(site); M blended row-pair at a time from LDS.
// ws = site base in s_w (100 dwords: pair s=(i*5+q) -> dwords 2s{A},2s+1{D})
__device__ __forceinline__ void site_step(const unsigned* __restrict__ ws,
                                          const h2 x2,
                                          const h2 (&src)[10][5],
                                          h2 (&dst)[10][5]) {
#pragma unroll
    for (int ip = 0; ip < 5; ++ip) {
        h2 m[10];   // m[q]: M[2ip][2q,2q+1]; m[5+q]: M[2ip+1][..]
        const uint4* w4 = (const uint4*)(ws + ip * 20);
#pragma unroll
        for (int t = 0; t < 5; ++t) {
            const uint4 w = w4[t];
            const h2 A0 = u2h(w.x), D0 = u2h(w.y);
            const h2 A1 = u2h(w.z), D1 = u2h(w.w);
            PKH_FMA(m[2 * t],     D0, x2, A0);
            PKH_FMA(m[2 * t + 1], D1, x2, A1);
        }
#pragma unroll
        for (int r = 0; r < 10; ++r) {
            if (ip == 0) {
#pragma unroll
                for (int q = 0; q < 5; ++q) PKH_MUL_LO(dst[r][q], m[q], src[r][0]);
            } else {
#pragma unroll
                for (int q = 0; q < 5; ++q) PKH_ACC_LO(dst[r][q], m[q], src[r][ip]);
            }
#pragma unroll
            for (int q = 0; q < 5; ++q) PKH_ACC_HI(dst[r][q], m[5 + q], src[r][ip]);
        }
    }
}

// ---------------- K1: one sample per lane, f16 chain ----------------------
__global__ __launch_bounds__(256, 1) void chunk_kernel(
    const float* __restrict__ x, const float* __restrict__ cores,
    uint4* __restrict__ pbuf, float* __restrict__ lbuf, int L) {
    __shared__ unsigned s_w[MAXL * 100];  // per-site f16 {2A,2D} pair dwords
    __shared__ float    s_x[256 * 17];    // x slice, stride 17

    const int c   = blockIdx.y;
    const int n0  = 1 + c * L;
    const int n1  = min(n0 + L, Nn);
    const int ns  = n1 - n0;
    const int tid = (int)threadIdx.x;
    const int b0  = (int)blockIdx.x * 256;
    const int b   = b0 + tid;

    // stage + convert weights (fused repack): pair e=(k,s): s=(i*5+q)
    for (int e = tid; e < ns * 50; e += 256) {
        const int k = e / 50, s = e - k * 50;
        const int i = s / 5, q = s - i * 5;
        const float* g = cores + (size_t)(n0 - 1 + k) * 200 + i * 20 + 2 * q;
        const float a0 = g[0], a1 = g[1], bb0 = g[10], bb1 = g[11];
        h2 A; A.x = (_Float16)(2.f * a0);         A.y = (_Float16)(2.f * a1);
        h2 D; D.x = (_Float16)(2.f * (bb0 - a0)); D.y = (_Float16)(2.f * (bb1 - a1));
        s_w[k * 100 + 2 * s]     = h2u(A);
        s_w[k * 100 + 2 * s + 1] = h2u(D);
    }
    // stage x slice (coalesced 16-wide)
    for (int e = tid; e < 256 * 16; e += 256) {
        const int bl = e >> 4, k = e & 15;
        if (k < ns) s_x[bl * 17 + k] = x[(size_t)(b0 + bl) * Nn + n0 + k];
    }
    __syncthreads();

    const float* __restrict__ xs = s_x + tid * 17;

    h2 p[10][5], q2[10][5];
    {   // first site: P = 2*M
        const _Float16 xh = (_Float16)xs[0];
        h2 x2; x2.x = xh; x2.y = xh;
#pragma unroll
        for (int r = 0; r < 10; ++r)
#pragma unroll
            for (int q = 0; q < 5; ++q) {
                const h2 A = u2h(s_w[r * 10 + 2 * q]);
                const h2 D = u2h(s_w[r * 10 + 2 * q + 1]);
                PKH_FMA(p[r][q], D, x2, A);
            }
    }
    int k = 1;
    while (k + 1 < ns) {        // ping-pong pairs, no copies
        {
            const _Float16 xh = (_Float16)xs[k];
            h2 x2; x2.x = xh; x2.y = xh;
            site_step(s_w + k * 100, x2, p, q2);
        }
        {
            const _Float16 xh = (_Float16)xs[k + 1];
            h2 x2; x2.x = xh; x2.y = xh;
            site_step(s_w + (k + 1) * 100, x2, q2, p);
        }
        k += 2;
    }
    if (k < ns) {               // odd tail
        const _Float16 xh = (_Float16)xs[k];
        h2 x2; x2.x = xh; x2.y = xh;
        site_step(s_w + k * 100, x2, p, q2);
#pragma unroll
        for (int r = 0; r < 10; ++r)
#pragma unroll
            for (int q = 0; q < 5; ++q) p[r][q] = q2[r][q];
    }

    // Frobenius renorm (f32 accumulate); correct the 2^ns pre-scale in lbuf
    float ss = 0.f;
#pragma unroll
    for (int r = 0; r < 10; ++r)
#pragma unroll
        for (int q = 0; q < 5; ++q) {
            ss = fmaf((float)p[r][q].x, (float)p[r][q].x, ss);
            ss = fmaf((float)p[r][q].y, (float)p[r][q].y, ss);
        }
    ss = fmaxf(ss, 1e-30f);
    const float rin = rsqrtf(ss);
    lbuf[(size_t)c * Bsz + b] = 0.5f * __logf(ss) - (float)ns * 0.69314718056f;

    const _Float16 rh = (_Float16)rin;
    h2 r2; r2.x = rh; r2.y = rh;
    unsigned od[52];
#pragma unroll
    for (int r = 0; r < 10; ++r)
#pragma unroll
        for (int q = 0; q < 5; ++q) od[r * 5 + q] = h2u(p[r][q] * r2);
    od[50] = 0; od[51] = 0;
    uint4* dst = pbuf + ((size_t)c * Bsz + b) * 13;
#pragma unroll
    for (int g = 0; g < 13; ++g) {
        uint4 v; v.x = od[4 * g]; v.y = od[4 * g + 1];
        v.z = od[4 * g + 2]; v.w = od[4 * g + 3];
        dst[g] = v;
    }
}

// ---------------- K2: combine chunks + logits (16 lanes per sample) --------
__global__ __launch_bounds__(256, 2) void combine_kernel(
    const float* __restrict__ x, const float* __restrict__ core0,
    const float* __restrict__ cls, const uint4* __restrict__ pbuf,
    const float* __restrict__ lbuf, float* __restrict__ out, int C) {
    const int tid   = (int)threadIdx.x;
    const int j     = tid & 15;
    const int jj    = (j < 10) ? j : 9;
    const int gbase = tid & 48;
    const int b     = blockIdx.x * 16 + (tid >> 4);

    float v[10];
    const float x0 = x[(size_t)b * Nn];
#pragma unroll
    for (int i = 0; i < 10; ++i) {
        const float c0 = core0[i], c1 = core0[10 + i];
        v[i] = fmaf(x0, c1 - c0, c0);
    }

    // depth-8 prefetch ring, statically indexed; f16 element flat idx = i*10+jj
    float w[8][10];
#pragma unroll
    for (int k8 = 0; k8 < 8; ++k8) {
        if (k8 < C) {
            const _Float16* pn =
                (const _Float16*)(pbuf + ((size_t)k8 * Bsz + b) * 13);
#pragma unroll
            for (int i = 0; i < 10; ++i) w[k8][i] = (float)pn[i * 10 + jj];
        }
    }

    float llog = 0.f;
    for (int cg = 0; cg < C; cg += 8) {
#pragma unroll
        for (int k8 = 0; k8 < 8; ++k8) {
            const int c = cg + k8;
            if (c >= C) break;
            float acc = 0.f;
#pragma unroll
            for (int i = 0; i < 10; ++i) acc = fmaf(v[i], w[k8][i], acc);
            if (j >= 10) acc = 0.f;
            llog += lbuf[(size_t)c * Bsz + b];
            if (k8 == 7 || c == C - 1) {   // deferred renorm
                float s = acc * acc;
                s += __shfl_xor(s, 1);
                s += __shfl_xor(s, 2);
                s += __shfl_xor(s, 4);
                s += __shfl_xor(s, 8);
                s = fmaxf(s, 1e-30f);
                llog += 0.5f * __logf(s);
                acc *= rsqrtf(s);
            }
#pragma unroll
            for (int i = 0; i < 10; ++i) v[i] = __shfl(acc, gbase + i);
            if (c + 8 < C) {               // refill the slot just consumed
                const _Float16* pn =
                    (const _Float16*)(pbuf + ((size_t)(c + 8) * Bsz + b) * 13);
#pragma unroll
                for (int i = 0; i < 10; ++i) w[k8][i] = (float)pn[i * 10 + jj];
            }
        }
    }

    if (j < 10) {
        float acc = llog;
#pragma unroll
        for (int i = 0; i < 10; ++i) acc = fmaf(v[i], cls[j * 10 + i], acc);
        out[(size_t)b * 10 + j] = acc;
    }
}

// ---------------- launch ----------------
extern "C" void kernel_launch(void* const* d_in, const int* in_sizes, int n_in,
                              void* d_out, int out_size, void* d_ws, size_t ws_size,
                              hipStream_t stream) {
    const float* x     = (const float*)d_in[0];
    const float* core0 = (const float*)d_in[1];
    const float* cores = (const float*)d_in[2];
    const float* cls   = (const float*)d_in[3];
    float* out = (float*)d_out;

    // pick L (sites/chunk): 12 default; grow only if workspace-tight
    int L = 12;
    int C = (NS + L - 1) / L;
    const size_t per_chunk = (size_t)Bsz * (13 * 16 + 4);   // pbuf + lbuf
    while ((size_t)C * per_chunk > ws_size && L < MAXL) {
        ++L;
        C = (NS + L - 1) / L;
    }
    uint4* pbuf = (uint4*)d_ws;
    float* lbuf = (float*)((char*)d_ws + (size_t)C * Bsz * 13 * 16);

    hipLaunchKernelGGL(chunk_kernel, dim3(Bsz / 256, C), dim3(256),
                       0, stream, x, cores, pbuf, lbuf, L);
    hipLaunchKernelGGL(combine_kernel, dim3(Bsz / 16), dim3(256),
                       0, stream, x, core0, cls, pbuf, lbuf, out, C);
}

// Round 10
// 86.175 us; speedup vs baseline: 1.5430x; 1.2059x over previous
//
#include <hip/hip_runtime.h>

// MPS classifier: logits[b,o] = (v/||v||)·cls[o] + log||v||,
//   v = head0(b) · M_1(b) · ... · M_783(b),  M_n = A_n + x[b,n]*(B_n - A_n).
// Chain associative; normalizations telescope.
//
// K1 (chunk_kernel): f16 chain math (v_pk_fma_f16), 2 LANES PER SAMPLE
//   (lane h owns rows 5h..5h+4) -- the proven no-spill register shape
//   (peak ~70 VGPR; the 1-sample/lane variant spilled in r2/r7/r9).
//   Weights fused-converted into LDS as f16 {A,D} pairs, x2.0 exact
//   pre-scale (corrected via lbuf -= ns*ln2): 25 ds_read_b128/site/wave.
//   LDS-pipe floor ~24.5us (was 49us f32).
// K2 (combine_kernel): f32 pbuf [c][b][100] contiguous (r6's 10us version),
//   depth-8 prefetch ring, renorm deferred to every 8th chunk.

typedef _Float16 h2 __attribute__((ext_vector_type(2)));

constexpr int Bsz  = 2048;
constexpr int Nn   = 784;
constexpr int NS   = 783;
constexpr int MAXL = 16;     // LDS capacity bound

// f16 VOP3P helpers. D = S0*S1 + S2 per half.
#define PKH_FMA(d, a, b, c) \
  asm("v_pk_fma_f16 %0, %1, %2, %3" : "=v"(d) : "v"(a), "v"(b), "v"(c))
#define PKH_ACC_LO(d, m, s) \
  asm("v_pk_fma_f16 %0, %1, %2, %0 op_sel:[0,0,0] op_sel_hi:[1,0,1]" \
      : "+v"(d) : "v"(m), "v"(s))
#define PKH_ACC_HI(d, m, s) \
  asm("v_pk_fma_f16 %0, %1, %2, %0 op_sel:[0,1,0] op_sel_hi:[1,1,1]" \
      : "+v"(d) : "v"(m), "v"(s))
#define PKH_MUL_LO(d, m, s) \
  asm("v_pk_mul_f16 %0, %1, %2 op_sel:[0,0] op_sel_hi:[1,0]" \
      : "=v"(d) : "v"(m), "v"(s))

__device__ __forceinline__ h2 u2h(unsigned u) {
    union { unsigned u; h2 h; } c; c.u = u; return c.h;
}
__device__ __forceinline__ unsigned h2u(h2 h) {
    union { unsigned u; h2 h; } c; c.h = h; return c.u;
}

// dst(5x10) = src(5x10) * M(site); M blended row-pair at a time from LDS.
// ws = site base in s_w (100 dwords; flat f16-pair s=(i*5+q) -> dwords 2s,2s+1)
__device__ __forceinline__ void site_step(const unsigned* __restrict__ ws,
                                          const h2 x2,
                                          const h2 (&src)[5][5],
                                          h2 (&dst)[5][5]) {
#pragma unroll
    for (int ip = 0; ip < 5; ++ip) {
        h2 m[10];   // m[q]: M[2ip][pair q]; m[5+q]: M[2ip+1][pair q]
        const uint4* w4 = (const uint4*)(ws + ip * 20);
#pragma unroll
        for (int t = 0; t < 5; ++t) {
            const uint4 w = w4[t];
            const h2 A0 = u2h(w.x), D0 = u2h(w.y);
            const h2 A1 = u2h(w.z), D1 = u2h(w.w);
            PKH_FMA(m[2 * t],     D0, x2, A0);
            PKH_FMA(m[2 * t + 1], D1, x2, A1);
        }
#pragma unroll
        for (int r = 0; r < 5; ++r) {
            if (ip == 0) {
#pragma unroll
                for (int q = 0; q < 5; ++q) PKH_MUL_LO(dst[r][q], m[q], src[r][0]);
            } else {
#pragma unroll
                for (int q = 0; q < 5; ++q) PKH_ACC_LO(dst[r][q], m[q], src[r][ip]);
            }
#pragma unroll
            for (int q = 0; q < 5; ++q) PKH_ACC_HI(dst[r][q], m[5 + q], src[r][ip]);
        }
    }
}

// ---------------- K1: f16 chain, 2 lanes per sample ----------------------
__global__ __launch_bounds__(256, 4) void chunk_kernel(
    const float* __restrict__ x, const float* __restrict__ cores,
    float* __restrict__ pbuf, float* __restrict__ lbuf, int L) {
    __shared__ unsigned s_w[MAXL * 100];  // per-site f16 {A,D} pair dwords
    __shared__ float    s_x[128 * 17];    // x slice, stride 17

    const int c   = blockIdx.y;
    const int n0  = 1 + c * L;
    const int n1  = min(n0 + L, Nn);
    const int ns  = n1 - n0;
    const int tid = (int)threadIdx.x;
    const int b0  = (int)blockIdx.x * 128;

    // stage + convert weights (fused repack): pair e=(k,s), s=(i*5+q)
    for (int e = tid; e < ns * 50; e += 256) {
        const int k = e / 50, s = e - k * 50;
        const int i = s / 5, q = s - i * 5;
        const float* g = cores + (size_t)(n0 - 1 + k) * 200 + i * 20 + 2 * q;
        const float a0 = g[0], a1 = g[1], bb0 = g[10], bb1 = g[11];
        h2 A; A.x = (_Float16)(2.f * a0);         A.y = (_Float16)(2.f * a1);
        h2 D; D.x = (_Float16)(2.f * (bb0 - a0)); D.y = (_Float16)(2.f * (bb1 - a1));
        s_w[k * 100 + 2 * s]     = h2u(A);
        s_w[k * 100 + 2 * s + 1] = h2u(D);
    }
    // stage x slice (coalesced 16-wide)
    for (int e = tid; e < 128 * 16; e += 256) {
        const int bl = e >> 4, k = e & 15;
        if (k < ns) s_x[bl * 17 + k] = x[(size_t)(b0 + bl) * Nn + n0 + k];
    }
    __syncthreads();

    const int h = tid & 1;              // row-half owner
    const int u = tid >> 1;             // sample slot 0..127
    const int b = b0 + u;
    const float* __restrict__ xs = s_x + u * 17;

    h2 p[5][5], q2[5][5];
    {   // first site: P = 2*M (rows 5h..5h+4)
        const _Float16 xh = (_Float16)xs[0];
        h2 x2; x2.x = xh; x2.y = xh;
#pragma unroll
        for (int r = 0; r < 5; ++r)
#pragma unroll
            for (int q = 0; q < 5; ++q) {
                const h2 A = u2h(s_w[(5 * h + r) * 10 + 2 * q]);
                const h2 D = u2h(s_w[(5 * h + r) * 10 + 2 * q + 1]);
                PKH_FMA(p[r][q], D, x2, A);
            }
    }
    int k = 1;
    while (k + 1 < ns) {        // ping-pong pairs, no copies
        {
            const _Float16 xh = (_Float16)xs[k];
            h2 x2; x2.x = xh; x2.y = xh;
            site_step(s_w + k * 100, x2, p, q2);
        }
        {
            const _Float16 xh = (_Float16)xs[k + 1];
            h2 x2; x2.x = xh; x2.y = xh;
            site_step(s_w + (k + 1) * 100, x2, q2, p);
        }
        k += 2;
    }
    if (k < ns) {               // odd tail
        const _Float16 xh = (_Float16)xs[k];
        h2 x2; x2.x = xh; x2.y = xh;
        site_step(s_w + k * 100, x2, p, q2);
#pragma unroll
        for (int r = 0; r < 5; ++r)
#pragma unroll
            for (int q = 0; q < 5; ++q) p[r][q] = q2[r][q];
    }

    // Frobenius renorm (f32 accumulate, pair-reduce across the 2 lanes);
    // correct the 2^ns pre-scale in lbuf.
    float ss = 0.f;
#pragma unroll
    for (int r = 0; r < 5; ++r)
#pragma unroll
        for (int q = 0; q < 5; ++q) {
            ss = fmaf((float)p[r][q].x, (float)p[r][q].x, ss);
            ss = fmaf((float)p[r][q].y, (float)p[r][q].y, ss);
        }
    ss += __shfl_xor(ss, 1);
    ss = fmaxf(ss, 1e-30f);
    const float rin = rsqrtf(ss);
    if (h == 0)
        lbuf[(size_t)c * Bsz + b] = 0.5f * __logf(ss) - (float)ns * 0.69314718056f;

    // store f32, per-sample CONTIGUOUS 100-float block (r6's proven K2 layout)
    float* dst = pbuf + ((size_t)c * Bsz + b) * 100;
#pragma unroll
    for (int r = 0; r < 5; ++r)
#pragma unroll
        for (int q = 0; q < 5; ++q) {
            float2 v;
            v.x = (float)p[r][q].x * rin;
            v.y = (float)p[r][q].y * rin;
            *(float2*)(dst + (5 * h + r) * 10 + 2 * q) = v;
        }
}

// ---------------- K2: combine chunks + logits (16 lanes per sample) --------
__global__ __launch_bounds__(256, 2) void combine_kernel(
    const float* __restrict__ x, const float* __restrict__ core0,
    const float* __restrict__ cls, const float* __restrict__ pbuf,
    const float* __restrict__ lbuf, float* __restrict__ out, int C) {
    const int tid   = (int)threadIdx.x;
    const int j     = tid & 15;
    const int jj    = (j < 10) ? j : 9;
    const int gbase = tid & 48;
    const int b     = blockIdx.x * 16 + (tid >> 4);

    float v[10];
    const float x0 = x[(size_t)b * Nn];
#pragma unroll
    for (int i = 0; i < 10; ++i) {
        const float c0 = core0[i], c1 = core0[10 + i];
        v[i] = fmaf(x0, c1 - c0, c0);
    }

    // depth-8 prefetch ring, statically indexed; per-chunk data contiguous
    float w[8][10];
#pragma unroll
    for (int k8 = 0; k8 < 8; ++k8) {
        if (k8 < C) {
            const float* pn = pbuf + ((size_t)k8 * Bsz + b) * 100 + jj;
#pragma unroll
            for (int i = 0; i < 10; ++i) w[k8][i] = pn[i * 10];
        }
    }

    float llog = 0.f;
    for (int cg = 0; cg < C; cg += 8) {
#pragma unroll
        for (int k8 = 0; k8 < 8; ++k8) {
            const int c = cg + k8;
            if (c >= C) break;
            float acc = 0.f;
#pragma unroll
            for (int i = 0; i < 10; ++i) acc = fmaf(v[i], w[k8][i], acc);
            if (j >= 10) acc = 0.f;
            llog += lbuf[(size_t)c * Bsz + b];
            if (k8 == 7 || c == C - 1) {   // deferred renorm
                float s = acc * acc;
                s += __shfl_xor(s, 1);
                s += __shfl_xor(s, 2);
                s += __shfl_xor(s, 4);
                s += __shfl_xor(s, 8);
                s = fmaxf(s, 1e-30f);
                llog += 0.5f * __logf(s);
                acc *= rsqrtf(s);
            }
#pragma unroll
            for (int i = 0; i < 10; ++i) v[i] = __shfl(acc, gbase + i);
            if (c + 8 < C) {               // refill the slot just consumed
                const float* pn = pbuf + ((size_t)(c + 8) * Bsz + b) * 100 + jj;
#pragma unroll
                for (int i = 0; i < 10; ++i) w[k8][i] = pn[i * 10];
            }
        }
    }

    if (j < 10) {
        float acc = llog;
#pragma unroll
        for (int i = 0; i < 10; ++i) acc = fmaf(v[i], cls[j * 10 + i], acc);
        out[(size_t)b * 10 + j] = acc;
    }
}

// ---------------- launch ----------------
extern "C" void kernel_launch(void* const* d_in, const int* in_sizes, int n_in,
                              void* d_out, int out_size, void* d_ws, size_t ws_size,
                              hipStream_t stream) {
    const float* x     = (const float*)d_in[0];
    const float* core0 = (const float*)d_in[1];
    const float* cores = (const float*)d_in[2];
    const float* cls   = (const float*)d_in[3];
    float* out = (float*)d_out;

    // pick L (sites/chunk): 12 default; grow only if workspace-tight
    int L = 12;
    int C = (NS + L - 1) / L;
    const size_t per_chunk = (size_t)Bsz * (100 * 4 + 4);   // pbuf + lbuf
    while ((size_t)C * per_chunk > ws_size && L < MAXL) {
        ++L;
        C = (NS + L - 1) / L;
    }
    float* pbuf = (float*)d_ws;
    float* lbuf = pbuf + (size_t)C * 100 * Bsz;

    hipLaunchKernelGGL(chunk_kernel, dim3(Bsz / 128, C), dim3(256),
                       0, stream, x, cores, pbuf, lbuf, L);
    hipLaunchKernelGGL(combine_kernel, dim3(Bsz / 16), dim3(256),
                       0, stream, x, core0, cls, pbuf, lbuf, out, C);
}